// Round 8
// baseline (417.766 us; speedup 1.0000x reference)
//
#include <hip/hip_runtime.h>

// out[b, f*TIME+t, e] = x[b, f*TIME+t, e] + pe_1d[f, e] + pe_1d[t, e]
// B=4, FREQ=256, TIME=512, E=512, fp32.
//
// Structure (rounds 3-6, kept): block owns a CONTIGUOUS 32-row chunk;
// e4/f/b constant per thread/block; pf hoisted; pe[t] eliminated via the
// rotation recurrence (pt(t+2) = R(2d)*pt(t), rot = pe row 2, exact table
// values, 8 FMAs/iter); fine grid (16384 blocks) for tail smoothing;
// unroll 8; nt LOAD on the one-touch x stream.
//
// Round 7 change (single lever): STORE IS TEMPORAL again. Evidence: the
// harness's fillBufferAligned hits 6.5-6.7 TB/s write-only with temporal
// stores on this same chip; our nt store (L2-bypass write path) is the
// last unexamined difference vs a pure copy. Writes are 50% of traffic.

typedef float f32x4 __attribute__((ext_vector_type(4)));

constexpr int  B_    = 4;
constexpr int  FREQ_ = 256;
constexpr int  TIME_ = 512;
constexpr int  E_    = 512;
constexpr int  E4    = E_ / 4;                 // 128 float4 per row
constexpr int  ROWS  = FREQ_ * TIME_;          // 131072 rows per batch
constexpr long N4T   = (long)B_ * ROWS * E4;   // 2^26 total float4

constexpr int BLOCK = 256;
constexpr int ITERS = 16;
constexpr int CHUNK = BLOCK * ITERS;           // 4096 float4 = 32 rows per block
constexpr int GRID  = (int)(N4T / CHUNK);      // 16384 blocks

static_assert(CHUNK % E4 == 0, "chunk row-aligned");
static_assert((CHUNK / E4) <= TIME_ && TIME_ % (CHUNK / E4) == 0, "f const per block");
static_assert(((long)ROWS * E4) % CHUNK == 0, "b const per block");

__global__ void __launch_bounds__(BLOCK)
pe2d_add_kernel(const f32x4* __restrict__ x,
                const f32x4* __restrict__ pe,
                f32x4* __restrict__ out)
{
    const int base    = blockIdx.x * CHUNK;          // < 2^26, fits int
    const int tid     = threadIdx.x;
    const int e4      = tid & (E4 - 1);
    const int dt      = tid >> 7;                    // 0 or 1: second row half
    const int rowbase = (base >> 7) & (ROWS - 1);    // row within batch
    const int f       = rowbase >> 9;                // constant per block
    const int t0      = (rowbase & (TIME_ - 1)) + dt;

    // one-time table loads (exact float32 table values)
    const f32x4 pf  = pe[f  * E4 + e4];              // freq component
    f32x4       pt  = pe[t0 * E4 + e4];              // time component at t0
    const f32x4 rot = pe[2  * E4 + e4];              // (sin 2d0, cos 2d0, sin 2d1, cos 2d1)

    int i = base + tid;

    #pragma unroll 8
    for (int it = 0; it < ITERS; ++it) {
        f32x4 v = __builtin_nontemporal_load(&x[i]); // one-touch read stream
        v = v + pf + pt;
        out[i] = v;                                  // TEMPORAL store (round-7 lever)
        i += BLOCK;                                  // +4 KB per iteration

        // advance time component: t -> t+2 via 2D rotation per (sin,cos) pair
        //   s' = s*cos2d + c*sin2d ; c' = c*cos2d - s*sin2d
        f32x4 np;
        np.x = pt.x * rot.y + pt.y * rot.x;
        np.y = pt.y * rot.y - pt.x * rot.x;
        np.z = pt.z * rot.w + pt.w * rot.z;
        np.w = pt.w * rot.w - pt.z * rot.z;
        pt = np;
    }
}

extern "C" void kernel_launch(void* const* d_in, const int* in_sizes, int n_in,
                              void* d_out, int out_size, void* d_ws, size_t ws_size,
                              hipStream_t stream)
{
    const f32x4* x  = (const f32x4*)d_in[0];   // (B, FREQ*TIME, E) fp32
    const f32x4* pe = (const f32x4*)d_in[1];   // (512, E) fp32
    f32x4* out = (f32x4*)d_out;

    pe2d_add_kernel<<<GRID, BLOCK, 0, stream>>>(x, pe, out);
}

// Round 9
// 384.158 us; speedup vs baseline: 1.0875x; 1.0875x over previous
//
#include <hip/hip_runtime.h>

// out[b, f*TIME+t, e] = x[b, f*TIME+t, e] + pe_1d[f, e] + pe_1d[t, e]
// B=4, FREQ=256, TIME=512, E=512, fp32.
//
// Round 8: COMPACT-SWEEP mapping (grid-stride, stride = total threads).
// Rationale: block-contiguous chunks put resident blocks' pointers exactly
// 2^18 B apart -> potential HBM channel-hash aliasing (all blocks sweep the
// same channel phase in lockstep). Compact sweep spreads the instantaneous
// footprint contiguously over all channels (same pattern as the 6.3-6.7 TB/s
// fill/copy kernels).
//
// Table-load elimination under this mapping (zero per-iter pe loads):
//   stride/iter = 2^22 float4 = 32768 rows -> t invariant per thread (pt
//   loaded once); f advances by exactly 64/iter -> pf advances by rotation
//   with rot = pe[64] (exact table values), reset to pf0 each batch (4 iters).
// nt load + nt store (round 6 config — round 7 proved temporal store −6%).

typedef float f32x4 __attribute__((ext_vector_type(4)));

constexpr int  B_    = 4;
constexpr int  FREQ_ = 256;
constexpr int  TIME_ = 512;
constexpr int  E_    = 512;
constexpr int  E4    = E_ / 4;                 // 128 float4 per row
constexpr int  ROWS  = FREQ_ * TIME_;          // 131072 rows per batch
constexpr long N4T   = (long)B_ * ROWS * E4;   // 2^26 total float4

constexpr int BLOCK    = 256;
constexpr int GRID     = 16384;
constexpr int NTHREADS = GRID * BLOCK;         // 2^22
constexpr int STRIDE   = NTHREADS;             // float4 units; = 32768 rows
constexpr int ITERS    = (int)(N4T / NTHREADS);        // 16
constexpr int ROWSTEP  = STRIDE / E4;                  // 32768 rows/iter
constexpr int ITERS_PER_BATCH = ROWS / ROWSTEP;        // 4
constexpr int FSTEP    = ROWSTEP / TIME_;              // f advances 64/iter

static_assert(ROWSTEP % TIME_ == 0, "t invariant per thread");
static_assert(ROWS % ROWSTEP == 0, "batch boundary aligns with iterations");
static_assert(ITERS == B_ * ITERS_PER_BATCH, "iter count");

__global__ void __launch_bounds__(BLOCK)
pe2d_add_kernel(const f32x4* __restrict__ x,
                const f32x4* __restrict__ pe,
                f32x4* __restrict__ out)
{
    const int i0  = blockIdx.x * BLOCK + threadIdx.x;  // < 2^22
    const int e4  = i0 & (E4 - 1);
    const int row = i0 >> 7;                           // < 32768
    const int t   = row & (TIME_ - 1);                 // invariant
    const int f0  = row >> 9;                          // < 64

    // one-time table loads (exact float32 table values)
    const f32x4 pt  = pe[t     * E4 + e4];             // time comp (invariant)
    const f32x4 pf0 = pe[f0    * E4 + e4];             // freq comp at f0
    const f32x4 rot = pe[FSTEP * E4 + e4];             // (sin 64d, cos 64d) pairs

    int i = i0;

    #pragma unroll
    for (int b = 0; b < B_; ++b) {
        f32x4 pf = pf0;                                // reset at batch boundary
        #pragma unroll
        for (int k = 0; k < ITERS_PER_BATCH; ++k) {
            f32x4 v = __builtin_nontemporal_load(&x[i]);
            v = v + pf + pt;
            __builtin_nontemporal_store(v, &out[i]);
            i += STRIDE;

            // advance freq component: f -> f+64 via 2D rotation per pair
            //   s' = s*cos + c*sin ; c' = c*cos - s*sin
            f32x4 np;
            np.x = pf.x * rot.y + pf.y * rot.x;
            np.y = pf.y * rot.y - pf.x * rot.x;
            np.z = pf.z * rot.w + pf.w * rot.z;
            np.w = pf.w * rot.w - pf.z * rot.z;
            pf = np;
        }
    }
}

extern "C" void kernel_launch(void* const* d_in, const int* in_sizes, int n_in,
                              void* d_out, int out_size, void* d_ws, size_t ws_size,
                              hipStream_t stream)
{
    const f32x4* x  = (const f32x4*)d_in[0];   // (B, FREQ*TIME, E) fp32
    const f32x4* pe = (const f32x4*)d_in[1];   // (512, E) fp32
    f32x4* out = (f32x4*)d_out;

    pe2d_add_kernel<<<GRID, BLOCK, 0, stream>>>(x, pe, out);
}